// Round 5
// baseline (132.876 us; speedup 1.0000x reference)
//
#include <hip/hip_runtime.h>
#include <hip/hip_bf16.h>

#define T_ROWS 16384
#define J_DIM  1024
#define D_DIM  512

typedef __attribute__((ext_vector_type(8))) short bf16x8;
typedef __attribute__((ext_vector_type(4))) float f32x4;
typedef unsigned short u16;

__device__ __forceinline__ u16 f2bf(float f) {
    union { float f; unsigned int u; } v; v.f = f;
    return (u16)((v.u + 0x7FFFu + ((v.u >> 16) & 1u)) >> 16);  // RNE
}
__device__ __forceinline__ float bf2f(u16 b) {
    union { unsigned int u; float f; } v; v.u = ((unsigned int)b) << 16;
    return v.f;
}

// async global->LDS, 16B per lane. LDS dest must be wave-uniform base + lane*16.
__device__ __forceinline__ void gload16(const void* g, void* l) {
    __builtin_amdgcn_global_load_lds(
        (__attribute__((address_space(1))) void*)(unsigned long long)(size_t)g,
        (__attribute__((address_space(3))) void*)(unsigned int)(size_t)l,
        16, 0, 0);
}

// ---------------------------------------------------------------------------
// m97-style 128x128 tile GEMM core, BK=32, bf16 MFMA 16x16x32 (kept).
// ---------------------------------------------------------------------------
template<int NT>
__device__ __forceinline__ void gemm_core(
    const u16* A, int lda, const u16* B, int ldb, u16* lds, f32x4 (&acc)[4][4])
{
    const int tid  = threadIdx.x;
    const int lane = tid & 63;
    const int w    = tid >> 6;
    const int wr   = w >> 1, wc = w & 1;
    const int fr   = lane & 15, quad = lane >> 4;

    const int srow = tid >> 2;
    const int ss   = (tid & 3) ^ ((srow >> 1) & 3);

    const u16* gA0 = A + (size_t)srow * lda + ss * 8;
    const u16* gA1 = A + (size_t)(srow + 64) * lda + ss * 8;
    const u16* gB0 = B + (size_t)srow * ldb + ss * 8;
    const u16* gB1 = B + (size_t)(srow + 64) * ldb + ss * 8;

    u16* As = lds;            // [2][4096]
    u16* Bs = lds + 8192;     // [2][4096]
    u16* dA0 = As + tid * 8;
    u16* dA1 = As + 2048 + tid * 8;
    u16* dB0 = Bs + tid * 8;
    u16* dB1 = Bs + 2048 + tid * 8;

    gload16(gA0, dA0); gload16(gA1, dA1);
    gload16(gB0, dB0); gload16(gB1, dB1);
    gA0 += 32; gA1 += 32; gB0 += 32; gB1 += 32;

    int offA[4], offB[4];
    #pragma unroll
    for (int i = 0; i < 4; ++i) {
        const int rA = wr * 64 + i * 16 + fr;
        offA[i] = rA * 32 + (quad ^ ((rA >> 1) & 3)) * 8;
        const int rB = wc * 64 + i * 16 + fr;
        offB[i] = rB * 32 + (quad ^ ((rB >> 1) & 3)) * 8;
    }
    __syncthreads();

    #pragma unroll 2
    for (int t = 0; t < NT; ++t) {
        const int cur = (t & 1) * 4096;
        const int nxt = 4096 - cur;
        if (t + 1 < NT) {
            gload16(gA0, dA0 + nxt); gload16(gA1, dA1 + nxt);
            gload16(gB0, dB0 + nxt); gload16(gB1, dB1 + nxt);
            gA0 += 32; gA1 += 32; gB0 += 32; gB1 += 32;
        }
        const u16* Ac = As + cur;
        const u16* Bc = Bs + cur;
        bf16x8 af[4], bfr[4];
        #pragma unroll
        for (int i = 0; i < 4; ++i) af[i]  = *(const bf16x8*)(Ac + offA[i]);
        #pragma unroll
        for (int i = 0; i < 4; ++i) bfr[i] = *(const bf16x8*)(Bc + offB[i]);
        #pragma unroll
        for (int mf = 0; mf < 4; ++mf)
            #pragma unroll
            for (int nf = 0; nf < 4; ++nf)
                acc[mf][nf] = __builtin_amdgcn_mfma_f32_16x16x32_bf16(
                    af[mf], bfr[nf], acc[mf][nf], 0, 0, 0);
        __syncthreads();
    }
}

// ---------------------------------------------------------------------------
// prep_u: uw2[j]=U_j.w2 ; Ub row-major bf16 (s_gemm B); Utp fragment-major
// ---------------------------------------------------------------------------
__global__ __launch_bounds__(128) void prep_u(
    const float* __restrict__ U, const float* __restrict__ Ws,
    float* __restrict__ uw2, u16* __restrict__ Ub, u16* __restrict__ Utp)
{
    const int j = blockIdx.x;
    const int t = threadIdx.x;
    const float4 u  = ((const float4*)(U + (size_t)j * D_DIM))[t];
    const float4 w2 = ((const float4*)(Ws + D_DIM))[t];
    float p = u.x * w2.x + u.y * w2.y + u.z * w2.z + u.w * w2.w;
    #pragma unroll
    for (int m = 1; m < 64; m <<= 1) p += __shfl_xor(p, m);
    __shared__ float red[2];
    if ((t & 63) == 0) red[t >> 6] = p;
    __syncthreads();
    if (t == 0) uw2[j] = red[0] + red[1];

    ushort4 v;
    v.x = f2bf(u.x); v.y = f2bf(u.y); v.z = f2bf(u.z); v.w = f2bf(u.w);
    ((ushort4*)(Ub + (size_t)j * D_DIM))[t] = v;

    const size_t jpart = (size_t)(j >> 5) * 512 + (size_t)(((j >> 3) & 3) * 128) + (j & 7);
    const u16 bs[4] = { v.x, v.y, v.z, v.w };
    #pragma unroll
    for (int s = 0; s < 4; ++s) {
        const int d = 4 * t + s;
        Utp[(size_t)(d >> 4) * 16384 + jpart + (size_t)(d & 15) * 8] = bs[s];
    }
}

// ---------------------------------------------------------------------------
// prep_h: hw1[i] = H_i.w1 ; Hq = bf16(H_i*w3) -> out u16 cols [3072:3584)
// ---------------------------------------------------------------------------
__global__ __launch_bounds__(128) void prep_h(
    const float* __restrict__ H, const float* __restrict__ Ws,
    float* __restrict__ hw1, u16* outU)
{
    const int i = blockIdx.x;
    const int t = threadIdx.x;
    const float4 h  = ((const float4*)(H + (size_t)i * D_DIM))[t];
    const float4 w1 = ((const float4*)Ws)[t];
    const float4 w3 = ((const float4*)(Ws + 2 * D_DIM))[t];
    float p = h.x * w1.x + h.y * w1.y + h.z * w1.z + h.w * w1.w;
    #pragma unroll
    for (int m = 1; m < 64; m <<= 1) p += __shfl_xor(p, m);
    __shared__ float red[2];
    if ((t & 63) == 0) red[t >> 6] = p;
    __syncthreads();
    if (t == 0) hw1[i] = red[0] + red[1];

    ushort4 q;
    q.x = f2bf(h.x * w3.x); q.y = f2bf(h.y * w3.y);
    q.z = f2bf(h.z * w3.z); q.w = f2bf(h.w * w3.w);
    *(ushort4*)(outU + (size_t)i * 4096 + 3072 + 4 * t) = q;
}

// ---------------------------------------------------------------------------
// s_gemm: S = Hq @ Ub^T + uw2 -> bf16 into out u16 cols [1024:2048);
// pmax[row*8+nb] = local row max.
// ---------------------------------------------------------------------------
__global__ __launch_bounds__(256) void s_gemm(
    u16* outU, const u16* __restrict__ Ub, const float* __restrict__ uw2,
    float* __restrict__ pmax)
{
    __shared__ u16 lds[16384];
    const int bid = blockIdx.x;                       // 1024
    const int swz = (bid & 7) * 128 + (bid >> 3);     // XCD swizzle (bijective)
    const int bm = swz >> 3, nb = swz & 7;

    f32x4 acc[4][4];
    #pragma unroll
    for (int i = 0; i < 4; ++i)
        #pragma unroll
        for (int j = 0; j < 4; ++j) acc[i][j] = (f32x4){0.f, 0.f, 0.f, 0.f};

    gemm_core<16>(outU + (size_t)bm * 128 * 4096 + 3072, 4096,
                  Ub + (size_t)nb * 128 * 512, 512, lds, acc);

    const int tid = threadIdx.x, lane = tid & 63, w = tid >> 6;
    const int wr = w >> 1, wc = w & 1, fr = lane & 15, quad = lane >> 4;
    int jc[4]; float u2[4];
    #pragma unroll
    for (int nf = 0; nf < 4; ++nf) {
        jc[nf] = nb * 128 + wc * 64 + nf * 16 + fr;
        u2[nf] = uw2[jc[nf]];
    }
    float* redf = (float*)lds;
    #pragma unroll
    for (int mf = 0; mf < 4; ++mf)
        #pragma unroll
        for (int m = 0; m < 4; ++m) {
            float mv = -1e30f;
            #pragma unroll
            for (int nf = 0; nf < 4; ++nf) {
                acc[mf][nf][m] += u2[nf];
                mv = fmaxf(mv, acc[mf][nf][m]);
            }
            mv = fmaxf(mv, __shfl_xor(mv, 1));
            mv = fmaxf(mv, __shfl_xor(mv, 2));
            mv = fmaxf(mv, __shfl_xor(mv, 4));
            mv = fmaxf(mv, __shfl_xor(mv, 8));
            if (fr == 0) redf[wc * 128 + wr * 64 + mf * 16 + quad * 4 + m] = mv;
        }
    __syncthreads();
    if (wc == 0 && fr == 0) {
        #pragma unroll
        for (int mf = 0; mf < 4; ++mf)
            #pragma unroll
            for (int m = 0; m < 4; ++m) {
                const int rr = wr * 64 + mf * 16 + quad * 4 + m;
                pmax[((size_t)bm * 128 + rr) * 8 + nb] =
                    fmaxf(redf[rr], redf[128 + rr]);
            }
    }
    #pragma unroll
    for (int mf = 0; mf < 4; ++mf)
        #pragma unroll
        for (int m = 0; m < 4; ++m) {
            const size_t row = (size_t)bm * 128 + wr * 64 + mf * 16 + quad * 4 + m;
            u16* rp = outU + row * 4096 + 1024;
            #pragma unroll
            for (int nf = 0; nf < 4; ++nf) rp[jc[nf]] = f2bf(acc[mf][nf][m]);
        }
}

// ---------------------------------------------------------------------------
// bsoft2: rstat_i = max_nb(pmax) + hw1_i; bvec = softmax(rstat) (one block)
// ---------------------------------------------------------------------------
__global__ __launch_bounds__(1024) void bsoft2(
    const float* __restrict__ pmax, const float* __restrict__ hw1,
    float* __restrict__ bvec)
{
    __shared__ float red[16];
    __shared__ float Msh, Lsh;
    const int t = threadIdx.x;
    float rs[16];
    #pragma unroll
    for (int e = 0; e < 16; ++e) {
        const int r = t + e * 1024;
        const float4 p0 = *(const float4*)(pmax + (size_t)r * 8);
        const float4 p1 = *(const float4*)(pmax + (size_t)r * 8 + 4);
        rs[e] = fmaxf(fmaxf(fmaxf(p0.x, p0.y), fmaxf(p0.z, p0.w)),
                      fmaxf(fmaxf(p1.x, p1.y), fmaxf(p1.z, p1.w))) + hw1[r];
    }
    float m = -1e30f;
    #pragma unroll
    for (int e = 0; e < 16; ++e) m = fmaxf(m, rs[e]);
    #pragma unroll
    for (int s = 1; s < 64; s <<= 1) m = fmaxf(m, __shfl_xor(m, s));
    if ((t & 63) == 0) red[t >> 6] = m;
    __syncthreads();
    if (t == 0) {
        float M = red[0];
        for (int i = 1; i < 16; ++i) M = fmaxf(M, red[i]);
        Msh = M;
    }
    __syncthreads();
    const float M = Msh;
    float l = 0.f;
    #pragma unroll
    for (int e = 0; e < 16; ++e) l += __expf(rs[e] - M);
    #pragma unroll
    for (int s = 1; s < 64; s <<= 1) l += __shfl_xor(l, s);
    if ((t & 63) == 0) red[t >> 6] = l;
    __syncthreads();
    if (t == 0) {
        float L = 0.f;
        for (int i = 0; i < 16; ++i) L += red[i];
        Lsh = L;
    }
    __syncthreads();
    const float invL = 1.f / Lsh;
    #pragma unroll
    for (int e = 0; e < 16; ++e) bvec[t + e * 1024] = __expf(rs[e] - M) * invL;
}

// ---------------------------------------------------------------------------
// h_tilde = b @ H (two-stage deterministic)
// ---------------------------------------------------------------------------
__global__ __launch_bounds__(512) void htilde_partial(
    const float* __restrict__ H, const float* __restrict__ b,
    float* __restrict__ part)
{
    const int blk = blockIdx.x;
    const int d = threadIdx.x;
    const int i0 = blk * 64;
    float s = 0.f;
    for (int rI = 0; rI < 64; ++rI)
        s += b[i0 + rI] * H[(size_t)(i0 + rI) * D_DIM + d];
    part[(size_t)blk * D_DIM + d] = s;
}

__global__ __launch_bounds__(512) void htilde_reduce(
    const float* __restrict__ part, float* __restrict__ ht)
{
    const int d = threadIdx.x;
    float s = 0.f;
    for (int p = 0; p < 256; ++p) s += part[(size_t)p * D_DIM + d];
    ht[d] = s;
}

// ---------------------------------------------------------------------------
// pv_fused: block = 32 rows x all 512 d, 512 threads, 2 blocks/CU.
// Phase1: stage S bf16 rows into LDS (chunk^(r&7) swizzle on global src).
// Phase2: in-LDS row softmax -> P. Phase3: AQ = P @ Utp (reg-pipelined B).
// Phase4: acc -> LDS f32 (stride 520) -> coalesced 256B-segment G stores.
// ---------------------------------------------------------------------------
__global__ __launch_bounds__(512, 4) void pv_fused(
    u16* outU, const u16* __restrict__ Utp, const float* __restrict__ H,
    const float* __restrict__ htld)
{
    __shared__ float SPf[32 * 520];          // 66560 B; aliased as u16 P buffer
    u16* SP = (u16*)SPf;                     // [32][1024] u16 (64 KB region)
    const int tid = threadIdx.x, lane = tid & 63, w = tid >> 6;
    const int fr = lane & 15, quad = lane >> 4;
    const int ib = blockIdx.x * 32;

    // Phase 1: stage S rows [ib, ib+32): 8 passes x 512 lanes x 16B
    #pragma unroll
    for (int p = 0; p < 8; ++p) {
        const int slot = p * 512 + tid;      // 0..4095
        const int r  = slot >> 7;            // 0..31
        const int c8 = slot & 127;
        gload16(outU + (size_t)(ib + r) * 4096 + 1024 + (size_t)((c8 ^ (r & 7)) * 8),
                SP + (size_t)slot * 8);
    }
    __syncthreads();

    // Phase 2: in-place softmax; wave w owns rows [4w, 4w+4)
    #pragma unroll
    for (int rr = 0; rr < 4; ++rr) {
        const int r = w * 4 + rr;
        u16* row = SP + (size_t)r * 1024;
        const int s0 = (lane ^ (r & 7)) * 8;
        const int s1 = ((lane + 64) ^ (r & 7)) * 8;
        bf16x8 x0 = *(bf16x8*)(row + s0);
        bf16x8 x1 = *(bf16x8*)(row + s1);
        float f0[8], f1[8];
        float mx = -1e30f;
        #pragma unroll
        for (int i = 0; i < 8; ++i) {
            f0[i] = bf2f((u16)x0[i]); f1[i] = bf2f((u16)x1[i]);
            mx = fmaxf(mx, fmaxf(f0[i], f1[i]));
        }
        #pragma unroll
        for (int s = 1; s < 64; s <<= 1) mx = fmaxf(mx, __shfl_xor(mx, s));
        float sum = 0.f;
        #pragma unroll
        for (int i = 0; i < 8; ++i) {
            f0[i] = __expf(f0[i] - mx); f1[i] = __expf(f1[i] - mx);
            sum += f0[i] + f1[i];
        }
        #pragma unroll
        for (int s = 1; s < 64; s <<= 1) sum += __shfl_xor(sum, s);
        const float inv = 1.f / sum;
        bf16x8 y0, y1;
        #pragma unroll
        for (int i = 0; i < 8; ++i) {
            y0[i] = (short)f2bf(f0[i] * inv);
            y1[i] = (short)f2bf(f1[i] * inv);
        }
        *(bf16x8*)(row + s0) = y0;
        *(bf16x8*)(row + s1) = y1;
    }
    __syncthreads();

    // Phase 3: AQ = P @ Utp; wave w owns d in [64w, 64w+64)
    f32x4 acc[2][4];
    #pragma unroll
    for (int i = 0; i < 2; ++i)
        #pragma unroll
        for (int j = 0; j < 4; ++j) acc[i][j] = (f32x4){0.f, 0.f, 0.f, 0.f};

    const u16* bp = Utp + (size_t)lane * 8;
    bf16x8 bA[4], bB[4];
    #pragma unroll
    for (int nf = 0; nf < 4; ++nf)
        bA[nf] = *(const bf16x8*)(bp + ((size_t)(w * 4 + nf) * 32) * 512);

    for (int ks = 0; ks < 32; ks += 2) {
        #pragma unroll
        for (int nf = 0; nf < 4; ++nf)
            bB[nf] = *(const bf16x8*)(bp + ((size_t)(w * 4 + nf) * 32 + ks + 1) * 512);
        bf16x8 a0[2];
        #pragma unroll
        for (int mf = 0; mf < 2; ++mf)
            a0[mf] = *(const bf16x8*)(SP + (size_t)(mf * 16 + fr) * 1024
                                         + (size_t)(((ks * 4 + quad) ^ (fr & 7)) * 8));
        #pragma unroll
        for (int mf = 0; mf < 2; ++mf)
            #pragma unroll
            for (int nf = 0; nf < 4; ++nf)
                acc[mf][nf] = __builtin_amdgcn_mfma_f32_16x16x32_bf16(
                    a0[mf], bA[nf], acc[mf][nf], 0, 0, 0);
        if (ks + 2 < 32) {
            #pragma unroll
            for (int nf = 0; nf < 4; ++nf)
                bA[nf] = *(const bf16x8*)(bp + ((size_t)(w * 4 + nf) * 32 + ks + 2) * 512);
        }
        bf16x8 a1[2];
        #pragma unroll
        for (int mf = 0; mf < 2; ++mf)
            a1[mf] = *(const bf16x8*)(SP + (size_t)(mf * 16 + fr) * 1024
                                         + (size_t)((((ks + 1) * 4 + quad) ^ (fr & 7)) * 8));
        #pragma unroll
        for (int mf = 0; mf < 2; ++mf)
            #pragma unroll
            for (int nf = 0; nf < 4; ++nf)
                acc[mf][nf] = __builtin_amdgcn_mfma_f32_16x16x32_bf16(
                    a1[mf], bB[nf], acc[mf][nf], 0, 0, 0);
    }
    __syncthreads();   // all P reads done; reuse LDS as f32 AQ buffer

    // Phase 4a: acc -> SPf [row][d] stride 520
    #pragma unroll
    for (int mf = 0; mf < 2; ++mf)
        #pragma unroll
        for (int m = 0; m < 4; ++m) {
            const int r = mf * 16 + quad * 4 + m;
            #pragma unroll
            for (int nf = 0; nf < 4; ++nf)
                SPf[r * 520 + w * 64 + nf * 16 + fr] = acc[mf][nf][m];
        }
    __syncthreads();

    // Phase 4b: coalesced G stores; thread t -> row tid>>4, 8 x float4
    {
        const int r = tid >> 4;              // 0..31
        const int l16 = tid & 15;
        const size_t grow = (size_t)ib + r;
        const float* hrow = H + grow * D_DIM;
        float* ob = (float*)outU + grow * 2048;
        #pragma unroll
        for (int i = 0; i < 8; ++i) {
            const int c = l16 * 4 + i * 64;
            const float4 h  = *(const float4*)(hrow + c);
            const float4 aq = *(const float4*)(&SPf[r * 520 + c]);
            const float4 hv = *(const float4*)(htld + c);
            float4 ha, hh;
            ha.x = h.x * aq.x; ha.y = h.y * aq.y; ha.z = h.z * aq.z; ha.w = h.w * aq.w;
            hh.x = h.x * hv.x; hh.y = h.y * hv.y; hh.z = h.z * hv.z; hh.w = h.w * hv.w;
            *(float4*)(ob + c)        = h;
            *(float4*)(ob + 512 + c)  = aq;
            *(float4*)(ob + 1024 + c) = ha;
            *(float4*)(ob + 1536 + c) = hh;
        }
    }
}

// ---------------------------------------------------------------------------
extern "C" void kernel_launch(void* const* d_in, const int* in_sizes, int n_in,
                              void* d_out, int out_size, void* d_ws, size_t ws_size,
                              hipStream_t stream)
{
    const float* H  = (const float*)d_in[0];
    const float* U  = (const float*)d_in[1];
    const float* Ws = (const float*)d_in[2];
    u16* outU = (u16*)d_out;

    float* uw2   = (float*)d_ws;                   // 1024
    float* hw1   = uw2 + 1024;                     // 16384
    float* bvec  = hw1 + T_ROWS;                   // 16384
    float* htld  = bvec + T_ROWS;                  // 512
    float* part  = htld + D_DIM;                   // 256*512
    float* pmax  = part + 256 * D_DIM;             // 16384*8
    u16*   Ub    = (u16*)(pmax + (size_t)T_ROWS * 8);   // 1 MB
    u16*   Utp   = Ub + (size_t)J_DIM * D_DIM;          // 1 MB

    hipLaunchKernelGGL(prep_u, dim3(J_DIM), dim3(128), 0, stream, U, Ws, uw2, Ub, Utp);
    hipLaunchKernelGGL(prep_h, dim3(T_ROWS), dim3(128), 0, stream, H, Ws, hw1, outU);
    hipLaunchKernelGGL(s_gemm, dim3(1024), dim3(256), 0, stream, outU, Ub, uw2, pmax);
    hipLaunchKernelGGL(bsoft2, dim3(1), dim3(1024), 0, stream, pmax, hw1, bvec);
    hipLaunchKernelGGL(htilde_partial, dim3(256), dim3(512), 0, stream, H, bvec, part);
    hipLaunchKernelGGL(htilde_reduce, dim3(1), dim3(512), 0, stream, part, htld);
    hipLaunchKernelGGL(pv_fused, dim3(T_ROWS / 32), dim3(512), 0, stream,
                       outU, Utp, H, htld);
}